// Round 8
// baseline (826.972 us; speedup 1.0000x reference)
//
#include <hip/hip_runtime.h>

#define N_PTS 32768
#define HID   100
#define STEPS 100

// Output layout (concatenated flat, fp32):
#define OFF_Z     0
#define OFF_MUXZ  262144
#define OFF_LTZX  327680
#define OFF_MUXZ_ 0
#undef OFF_MUXZ
#define OFF_MUXZ  65536
#define OFF_LSXZ  163840
#define OFF_MUZX  262144
#define OFF_LTZX  327680
#define OFF_MUZ   360448
#define OFF_LTZ   425984

typedef float v2f __attribute__((ext_vector_type(2)));

#if __has_builtin(__builtin_elementwise_fma)
#define FMA2(a, b, c) __builtin_elementwise_fma((a), (b), (c))
#else
#define FMA2(a, b, c) ((a) * (b) + (c))
#endif

__device__ __forceinline__ v2f splat(float x) { v2f r; r.x = x; r.y = x; return r; }

// Butterfly sum across a quad of lanes via DPP quad_perm (xor1=0xB1, xor2=0x4E).
__device__ __forceinline__ float qreduce(float v) {
  v += __int_as_float(__builtin_amdgcn_update_dpp(0, __float_as_int(v), 0xB1, 0xF, 0xF, true));
  v += __int_as_float(__builtin_amdgcn_update_dpp(0, __float_as_int(v), 0x4E, 0xF, 0xF, true));
  return v;
}

// ---- prep: pack the per-j head-weight table into d_ws ----
// gtab[j] = {W01, W11, m0, s0}, {m1, s1, m2, s2}   (2 float4 per j, 3.2 KB)
__global__ __launch_bounds__(128) void prep_kernel(
    const float* __restrict__ Wd1, const float* __restrict__ Wdmu,
    const float* __restrict__ Wds, float4* __restrict__ gtab)
{
  const int j = threadIdx.x;
  if (j < HID) {
    const float w0 = Wd1[j], w1 = Wd1[HID + j];
    float4 g0, g1;
    g0.x = w0 * w1;      g0.y = w1 * w1;
    g0.z = Wdmu[j*3+0];  g0.w = Wds[j*3+0];
    g1.x = Wdmu[j*3+1];  g1.y = Wds[j*3+1];
    g1.z = Wdmu[j*3+2];  g1.w = Wds[j*3+2];
    gtab[j*2+0] = g0;
    gtab[j*2+1] = g1;
  }
}

// ---------------- Encoder: x -> h1 -> h2 -> (mu_zx, log_t_zx) ----------------
__global__ __launch_bounds__(128, 1) void enc_kernel(
    const float* __restrict__ x,
    const float* __restrict__ We1, const float* __restrict__ be1,
    const float* __restrict__ We2, const float* __restrict__ be2,
    const float* __restrict__ Wmu, const float* __restrict__ bmu,
    const float* __restrict__ Wlt, const float* __restrict__ blt,
    const float* __restrict__ b_muz, const float* __restrict__ b_ltz,
    float* __restrict__ out)
{
  const int tid = threadIdx.x;
  const int w   = tid >> 6;           // wave 0/1
  const int pb  = tid & 63;           // point within block
  const int p   = blockIdx.x * 64 + pb;
  const int ob  = __builtin_amdgcn_readfirstlane(w * 50);

  const float x0 = x[p*3+0], x1 = x[p*3+1], x2 = x[p*3+2];

  v2f acc2[25];
  #pragma unroll
  for (int i = 0; i < 25; ++i) { acc2[i].x = 0.f; acc2[i].y = 0.f; }

  for (int k = 0; k < HID; ++k) {
    float a   = fmaf(x0, We1[k], fmaf(x1, We1[HID+k], fmaf(x2, We1[2*HID+k], be1[k])));
    float sig = 1.f / (1.f + __expf(-a));
    float h1  = a * sig;
    const v2f hh = splat(h1);
    const v2f* row2 = (const v2f*)(We2 + k*HID + ob);
    #pragma unroll
    for (int oo = 0; oo < 25; ++oo) acc2[oo] = FMA2(hh, row2[oo], acc2[oo]);
  }

  float m0 = 0.f, m1 = 0.f, lt = 0.f;
  #pragma unroll
  for (int oo = 0; oo < 25; ++oo) {
    #pragma unroll
    for (int h = 0; h < 2; ++h) {
      const int o = ob + 2*oo + h;
      float a   = (h ? acc2[oo].y : acc2[oo].x) + be2[o];
      float sig = 1.f / (1.f + __expf(-a));
      float h2  = a * sig;
      m0 = fmaf(h2, Wmu[o*2+0], m0);
      m1 = fmaf(h2, Wmu[o*2+1], m1);
      lt = fmaf(h2, Wlt[o],     lt);
    }
  }

  __shared__ float red[2][64][3];
  red[w][pb][0] = m0; red[w][pb][1] = m1; red[w][pb][2] = lt;
  __syncthreads();
  if (w == 0) {
    m0 += red[1][pb][0] + bmu[0];
    m1 += red[1][pb][1] + bmu[1];
    lt += red[1][pb][2] + blt[0];
    out[OFF_MUZX + p*2+0] = m0;
    out[OFF_MUZX + p*2+1] = m1;
    out[OFF_LTZX + p]     = lt;
    out[OFF_MUZ  + p*2+0] = b_muz[0];
    out[OFF_MUZ  + p*2+1] = b_muz[1];
    out[OFF_LTZ  + p]     = b_ltz[0];
  }
}

// ------------- SDE: 100 Euler-Maruyama steps on the pullback metric ----------
// r3's verified structure (4 lanes/point, 25 j/lane, partial unroll 5), but the
// per-j weight stream is SPLIT ACROSS TWO PIPES:
//   LDS  (1 ds_read_b128):        {W0, W1, b, W00}
//   VMEM (2 global_load_dwordx4): {W01,W11,m0,s0}, {m1,s1,m2,s2}  (L1-resident)
// r2/r3/r7 fit wall = T_LDS + T_VALU (no overlap); this cuts T_LDS ~3x and
// puts the rest on the VMEM pipe, which runs parallel to LDS.
// All 30 accumulators are flat named scalars (no private arrays -> no spill).
__global__ __launch_bounds__(256, 2) void sde_kernel(
    const float* __restrict__ Wd1,  const float* __restrict__ bd1,
    const float* __restrict__ bdmu, const float* __restrict__ bds,
    const float4* __restrict__ gtab,
    const float* __restrict__ noise,
    float* __restrict__ out)
{
  __shared__ __align__(16) float4 wrec4[HID];
  const int tid = threadIdx.x;
  if (tid < HID) {
    const float w0 = Wd1[tid], w1 = Wd1[HID + tid];
    float4 r; r.x = w0; r.y = w1; r.z = bd1[tid]; r.w = w0 * w0;
    wrec4[tid] = r;
  }
  __syncthreads();

  const int l     = tid & 3;                    // lane within quad
  const int p     = blockIdx.x * 64 + (tid >> 2);
  const int jbase = l * 25;

  float z0 = out[OFF_MUZX + p*2+0];
  float z1 = out[OFF_MUZX + p*2+1];
  const float sdt = __expf(out[OFF_LTZX + p]) * 0.1f;  // sqrt(dt) = exp(lt)/sqrt(100)

  const float2* __restrict__ noise2 = (const float2*)noise;

  for (int step = 0; step < STEPS; ++step) {
    // issue the noise load early; latency hides under the j-loop
    const float2 nz = noise2[(size_t)step*N_PTS + p];

    float jm00=0.f,jm01=0.f,jm10=0.f,jm11=0.f,jm20=0.f,jm21=0.f;
    float js00=0.f,js01=0.f,js10=0.f,js11=0.f,js20=0.f,js21=0.f;
    float km00=0.f,km01=0.f,km02=0.f,km10=0.f,km11=0.f,km12=0.f,km20=0.f,km21=0.f,km22=0.f;
    float ks00=0.f,ks01=0.f,ks02=0.f,ks10=0.f,ks11=0.f,ks12=0.f,ks20=0.f,ks21=0.f,ks22=0.f;

    #pragma unroll 5
    for (int jj = 0; jj < 25; ++jj) {
      const int j = jbase + jj;
      const float4 wa = wrec4[j];        // LDS: {W0, W1, b, W00}
      const float4 g0 = gtab[j*2+0];     // L1:  {W01, W11, m0, s0}
      const float4 g1 = gtab[j*2+1];     // L1:  {m1, s1, m2, s2}
      float a   = fmaf(z0, wa.x, fmaf(z1, wa.y, wa.z));
      float e   = __expf(-a);
      float sig = __builtin_amdgcn_rcpf(1.f + e);
      float t1  = 1.f - sig;
      float pp  = sig * t1;
      float u   = fmaf(a, pp, sig);                          // swish'
      float u2  = pp * fmaf(a, fmaf(-2.f, sig, 1.f), 2.f);   // swish''
      float c0  = u*wa.x,  c1  = u*wa.y;
      float q00 = u2*wa.w, q01 = u2*g0.x, q11 = u2*g0.y;
      jm00 = fmaf(g0.z, c0,  jm00); jm01 = fmaf(g0.z, c1,  jm01);
      js00 = fmaf(g0.w, c0,  js00); js01 = fmaf(g0.w, c1,  js01);
      km00 = fmaf(g0.z, q00, km00); km01 = fmaf(g0.z, q01, km01); km02 = fmaf(g0.z, q11, km02);
      ks00 = fmaf(g0.w, q00, ks00); ks01 = fmaf(g0.w, q01, ks01); ks02 = fmaf(g0.w, q11, ks02);
      jm10 = fmaf(g1.x, c0,  jm10); jm11 = fmaf(g1.x, c1,  jm11);
      js10 = fmaf(g1.y, c0,  js10); js11 = fmaf(g1.y, c1,  js11);
      km10 = fmaf(g1.x, q00, km10); km11 = fmaf(g1.x, q01, km11); km12 = fmaf(g1.x, q11, km12);
      ks10 = fmaf(g1.y, q00, ks10); ks11 = fmaf(g1.y, q01, ks11); ks12 = fmaf(g1.y, q11, ks12);
      jm20 = fmaf(g1.z, c0,  jm20); jm21 = fmaf(g1.z, c1,  jm21);
      js20 = fmaf(g1.w, c0,  js20); js21 = fmaf(g1.w, c1,  js21);
      km20 = fmaf(g1.z, q00, km20); km21 = fmaf(g1.z, q01, km21); km22 = fmaf(g1.z, q11, km22);
      ks20 = fmaf(g1.w, q00, ks20); ks21 = fmaf(g1.w, q01, ks21); ks22 = fmaf(g1.w, q11, ks22);
    }
    // complete the j-sums across the quad (linear, so reduce before products)
    jm00=qreduce(jm00); jm01=qreduce(jm01); jm10=qreduce(jm10);
    jm11=qreduce(jm11); jm20=qreduce(jm20); jm21=qreduce(jm21);
    js00=qreduce(js00); js01=qreduce(js01); js10=qreduce(js10);
    js11=qreduce(js11); js20=qreduce(js20); js21=qreduce(js21);
    km00=qreduce(km00); km01=qreduce(km01); km02=qreduce(km02);
    km10=qreduce(km10); km11=qreduce(km11); km12=qreduce(km12);
    km20=qreduce(km20); km21=qreduce(km21); km22=qreduce(km22);
    ks00=qreduce(ks00); ks01=qreduce(ks01); ks02=qreduce(ks02);
    ks10=qreduce(ks10); ks11=qreduce(ks11); ks12=qreduce(ks12);
    ks20=qreduce(ks20); ks21=qreduce(ks21); ks22=qreduce(ks22);

    const float Jm[3][2] = {{jm00,jm01},{jm10,jm11},{jm20,jm21}};
    const float Js[3][2] = {{js00,js01},{js10,js11},{js20,js21}};
    const float Km[3][3] = {{km00,km01,km02},{km10,km11,km12},{km20,km21,km22}};
    const float Ks[3][3] = {{ks00,ks01,ks02},{ks10,ks11,ks12},{ks20,ks21,ks22}};

    // G = J^T J (2x2 sym)
    float G00=0.f, G01=0.f, G11=0.f;
    #pragma unroll
    for (int o = 0; o < 3; ++o) {
      G00 += Jm[o][0]*Jm[o][0] + Js[o][0]*Js[o][0];
      G01 += Jm[o][0]*Jm[o][1] + Js[o][0]*Js[o][1];
      G11 += Jm[o][1]*Jm[o][1] + Js[o][1]*Js[o][1];
    }
    // D[c][l] = dG[km]/dz_l (sym in k,m)
    float D00=0.f, D01=0.f, D10=0.f, D11=0.f, D20=0.f, D21=0.f;
    #pragma unroll
    for (int o = 0; o < 3; ++o) {
      D00 += 2.f*(Km[o][0]*Jm[o][0] + Ks[o][0]*Js[o][0]);
      D01 += 2.f*(Km[o][1]*Jm[o][0] + Ks[o][1]*Js[o][0]);
      D10 += Km[o][0]*Jm[o][1] + Jm[o][0]*Km[o][1] + Ks[o][0]*Js[o][1] + Js[o][0]*Ks[o][1];
      D11 += Km[o][1]*Jm[o][1] + Jm[o][0]*Km[o][2] + Ks[o][1]*Js[o][1] + Js[o][0]*Ks[o][2];
      D20 += 2.f*(Km[o][1]*Jm[o][1] + Ks[o][1]*Js[o][1]);
      D21 += 2.f*(Km[o][2]*Jm[o][1] + Ks[o][2]*Js[o][1]);
    }
    const float det = fmaf(G00, G11, -G01*G01);
    const float id  = __builtin_amdgcn_rcpf(det);
    const float i00 = G11*id, i01 = -G01*id, i11 = G00*id;
    // T[k,l,m] = Dg[k,m,l] + Dg[l,m,k] - Dg[k,l,m]
    const float T000 = D00;
    const float T001 = 2.f*D10 - D01;
    const float T010 = D01;
    const float T011 = D20;
    const float T110 = 2.f*D11 - D20;
    const float T111 = D21;
    // Chris[i][c] = 0.5 * ginv[i,m] T[k,l,m]
    const float C00 = 0.5f*(i00*T000 + i01*T001);
    const float C01 = 0.5f*(i00*T010 + i01*T011);
    const float C02 = 0.5f*(i00*T110 + i01*T111);
    const float C10 = 0.5f*(i01*T000 + i11*T001);
    const float C11 = 0.5f*(i01*T010 + i11*T011);
    const float C12 = 0.5f*(i01*T110 + i11*T111);
    // drift[i] = 0.5 * ginv[j,k] Chris[i,j,k]
    const float dr0 = 0.5f*(i00*C00 + 2.f*i01*C01 + i11*C02);
    const float dr1 = 0.5f*(i00*C10 + 2.f*i01*C11 + i11*C12);

    const float dw0 = sdt*nz.x, dw1 = sdt*nz.y;
    z0 += dr0 + i00*dw0 + i01*dw1;   // + ginv @ dW
    z1 += dr1 + i01*dw0 + i11*dw1;
  }

  // ---- final decode on z ----
  float ma0=0.f, ma1=0.f, ma2=0.f, sa0=0.f, sa1=0.f, sa2=0.f;
  #pragma unroll 5
  for (int jj = 0; jj < 25; ++jj) {
    const int j = jbase + jj;
    const float4 wa = wrec4[j];
    const float4 g0 = gtab[j*2+0];
    const float4 g1 = gtab[j*2+1];
    float a   = fmaf(z0, wa.x, fmaf(z1, wa.y, wa.z));
    float sig = __builtin_amdgcn_rcpf(1.f + __expf(-a));
    float h   = a * sig;
    ma0 = fmaf(h, g0.z, ma0); sa0 = fmaf(h, g0.w, sa0);
    ma1 = fmaf(h, g1.x, ma1); sa1 = fmaf(h, g1.y, sa1);
    ma2 = fmaf(h, g1.z, ma2); sa2 = fmaf(h, g1.w, sa2);
  }
  ma0=qreduce(ma0); ma1=qreduce(ma1); ma2=qreduce(ma2);
  sa0=qreduce(sa0); sa1=qreduce(sa1); sa2=qreduce(sa2);

  if (l == 0) {
    out[OFF_Z + p*2+0] = z0;
    out[OFF_Z + p*2+1] = z1;
    out[OFF_MUXZ + p*3+0] = ma0 + bdmu[0];
    out[OFF_MUXZ + p*3+1] = ma1 + bdmu[1];
    out[OFF_MUXZ + p*3+2] = ma2 + bdmu[2];
    out[OFF_LSXZ + p*3+0] = sa0 + bds[0];
    out[OFF_LSXZ + p*3+1] = sa1 + bds[1];
    out[OFF_LSXZ + p*3+2] = sa2 + bds[2];
  }
}

extern "C" void kernel_launch(void* const* d_in, const int* in_sizes, int n_in,
                              void* d_out, int out_size, void* d_ws, size_t ws_size,
                              hipStream_t stream) {
  (void)in_sizes; (void)n_in; (void)ws_size; (void)out_size;
  const float* x    = (const float*)d_in[0];
  const float* We1  = (const float*)d_in[1];
  const float* be1  = (const float*)d_in[2];
  const float* We2  = (const float*)d_in[3];
  const float* be2  = (const float*)d_in[4];
  const float* Wmu  = (const float*)d_in[5];
  const float* bmu  = (const float*)d_in[6];
  const float* Wlt  = (const float*)d_in[7];
  const float* blt  = (const float*)d_in[8];
  const float* Wd1  = (const float*)d_in[9];
  const float* bd1  = (const float*)d_in[10];
  const float* Wdmu = (const float*)d_in[11];
  const float* bdmu = (const float*)d_in[12];
  const float* Wds  = (const float*)d_in[13];
  const float* bds  = (const float*)d_in[14];
  const float* bmz  = (const float*)d_in[15];
  const float* blz  = (const float*)d_in[16];
  const float* noise= (const float*)d_in[17];
  float* out = (float*)d_out;
  float4* gtab = (float4*)d_ws;   // 100 x 2 float4 = 3.2 KB

  prep_kernel<<<1, 128, 0, stream>>>(Wd1, Wdmu, Wds, gtab);
  enc_kernel<<<512, 128, 0, stream>>>(x, We1, be1, We2, be2, Wmu, bmu, Wlt, blt,
                                      bmz, blz, out);
  sde_kernel<<<512, 256, 0, stream>>>(Wd1, bd1, bdmu, bds, gtab, noise, out);
}